// Round 5
// baseline (426.816 us; speedup 1.0000x reference)
//
#include <hip/hip_runtime.h>
#include <hip/hip_bf16.h>
#include <hip/hip_cooperative_groups.h>

namespace cg = cooperative_groups;

// QuIP#-style quantized linear. R15: one cooperative mega-kernel.
// Model (validated across R11-R14): per-CU vmem request wall ~215cy/req /
// ~64 outstanding. qgemm = 32768 random 16B gathers/CU = 46us, irreducible
// (8 structural nulls). R13's small kernels are request-light (8-16
// req/thread, ~3-5us each) but the 5-dispatch chain pays ~10-13us per
// inter-kernel gap (R13 ~128 = 65 body + 4 gaps + launch; R14's fused zsum
// added 16K req/CU = +23us body for -20us gaps -> net loss. Model fits both).
// R15: R13 bodies VERBATIM, glued with cg::grid().sync() (4 syncs ~3-5us
// each) inside one hipLaunchCooperativeKernel dispatch. 256 blocks x 512
// thr, 64KB LDS -> co-residency guaranteed. Fallback: R13 5-kernel path if
// cooperativeLaunch unsupported.

typedef __attribute__((ext_vector_type(16))) float f32x16;
typedef __attribute__((ext_vector_type(8))) __bf16 bf16x8;
typedef __attribute__((ext_vector_type(4))) __bf16 bf16x4;
typedef __attribute__((ext_vector_type(4))) int i32x4;

#define IN_F 8192
#define OUT_F 8192
#define TOKENS 32
#define KSPLIT 8
#define KCHUNK 1024
#define CH (KCHUNK / 8)            // 128 16B-chunks per token row in LDS
#define GROUPS (KCHUNK / 32)       // 32 pipeline groups (4 codes each)
#define DG 5                       // gather lookahead (groups)
#define DI 7                       // idx lookahead (groups)
#define INV_SQRT_8192 0.011048543456039806f
#define PAD(i) ((i) + ((i) >> 5))

#if __has_builtin(__builtin_amdgcn_raw_buffer_load_b128) && \
    __has_builtin(__builtin_amdgcn_make_buffer_rsrc)
#define HAVE_BUF 1
#else
#define HAVE_BUF 0
#endif

// ---------------- register FWHT-8 (strided bits, order-free) --------------
__device__ inline void fwht8_reg(float* v) {
    #pragma unroll
    for (int h = 1; h < 8; h <<= 1)
        #pragma unroll
        for (int i = 0; i < 8; i += 2 * h)
            #pragma unroll
            for (int j = 0; j < h; ++j) {
                float a = v[i + j], b = v[i + j + h];
                v[i + j] = a + b;
                v[i + j + h] = a - b;
            }
}

// ---- FWHT-1024 (bits 0-9), 256 threads, radix-4, 5 stages --------------
// entry: v[j] = element 4*tid+j. exit: v[j] = element tid + j*256.
__device__ inline void fwht1024(float v[4], float* st, int tid) {
    {   // stage 0 (bits 0-1) in registers
        float t0 = v[0] + v[1], t1 = v[0] - v[1];
        float t2 = v[2] + v[3], t3 = v[2] - v[3];
        v[0] = t0 + t2; v[1] = t1 + t3; v[2] = t0 - t2; v[3] = t1 - t3;
    }
    int pos[4] = {4 * tid, 4 * tid + 1, 4 * tid + 2, 4 * tid + 3};
    #pragma unroll
    for (int s = 1; s < 5; ++s) {
        #pragma unroll
        for (int j = 0; j < 4; ++j) st[PAD(pos[j])] = v[j];
        __syncthreads();
        const int q = 1 << (2 * s);
        const int i = ((tid >> (2 * s)) << (2 * s + 2)) + (tid & (q - 1));
        #pragma unroll
        for (int j = 0; j < 4; ++j) { pos[j] = i + j * q; v[j] = st[PAD(pos[j])]; }
        __syncthreads();   // protect next stage's writes (WAR)
        float t0 = v[0] + v[1], t1 = v[0] - v[1];
        float t2 = v[2] + v[3], t3 = v[2] - v[3];
        v[0] = t0 + t2; v[1] = t1 + t3; v[2] = t0 - t2; v[3] = t1 - t3;
    }
}

// ---------------- shared phase bodies ----------------
__device__ inline void cvt_body(const float* __restrict__ cb,
                                __bf16* __restrict__ cbb, int g) {
    float4 vv = ((const float4*)cb)[g];
    bf16x4 o;
    o[0] = (__bf16)vv.x; o[1] = (__bf16)vv.y;
    o[2] = (__bf16)vv.z; o[3] = (__bf16)vv.w;
    ((bf16x4*)cbb)[g] = o;
}

__device__ inline void prepA_body(const float* __restrict__ x,
                                  const float* __restrict__ su,
                                  float* __restrict__ xw, int task) {
    const int t = task >> 10, c = task & 1023;
    float v[8];
    #pragma unroll
    for (int k = 0; k < 8; ++k)
        v[k] = x[t * IN_F + k * 1024 + c] * su[k * 1024 + c];
    fwht8_reg(v);
    #pragma unroll
    for (int k = 0; k < 8; ++k)
        xw[t * IN_F + k * 1024 + c] = v[k];
}

__device__ inline void prepB_body(const float* __restrict__ xw,
                                  __bf16* __restrict__ xh,
                                  float* st, int id, int tl) {
    const int t = id >> 3, ch = id & 7;
    float4 f = ((const float4*)(xw + (size_t)t * IN_F + ch * 1024))[tl];
    float v[4] = {f.x, f.y, f.z, f.w};
    fwht1024(v, st, tl);
    __bf16* dst = xh + (size_t)t * IN_F + ch * 1024;
    #pragma unroll
    for (int j = 0; j < 4; ++j)
        dst[tl + j * 256] = (__bf16)(v[j] * INV_SQRT_8192);
}

__device__ inline void zsumA_body(const __bf16* __restrict__ zpart,
                                  float* __restrict__ z1,
                                  float* st, int id, int tl) {
    const int t = id >> 3, ch = id & 7;
    float v[4] = {0.f, 0.f, 0.f, 0.f};
    #pragma unroll
    for (int ks = 0; ks < KSPLIT; ++ks) {
        bf16x4 b = *(const bf16x4*)(zpart +
                     ((size_t)(ks * TOKENS + t)) * OUT_F + ch * 1024 + tl * 4);
        v[0] += (float)b[0]; v[1] += (float)b[1];
        v[2] += (float)b[2]; v[3] += (float)b[3];
    }
    fwht1024(v, st, tl);
    float* dst = z1 + (size_t)t * OUT_F + ch * 1024;
    #pragma unroll
    for (int j = 0; j < 4; ++j)
        dst[tl + j * 256] = v[j];
}

__device__ inline void zsumB_body(const float* __restrict__ z1,
                                  const float* __restrict__ sv,
                                  const float* __restrict__ wscale,
                                  float* __restrict__ out, int task) {
    const int t = task >> 10, c = task & 1023;
    float v[8];
    #pragma unroll
    for (int k = 0; k < 8; ++k)
        v[k] = z1[t * OUT_F + k * 1024 + c];
    fwht8_reg(v);
    const float sc = INV_SQRT_8192 * wscale[0];
    #pragma unroll
    for (int k = 0; k < 8; ++k)
        out[t * OUT_F + k * 1024 + c] = v[k] * sc * sv[k * 1024 + c];
}

// ---- qgemm body (R11 champion, verbatim structure) ----
__device__ inline void qgemm_body(const int* __restrict__ qidxs,
                                  const __bf16* __restrict__ cb,
                                  const __bf16* __restrict__ xh,
                                  __bf16* __restrict__ zpart,
                                  __bf16* xt, int bid, int tid) {
    const int ks = bid & (KSPLIT - 1);
    const int nb = bid >> 3;
    const int wave = tid >> 6, lane = tid & 63;
    const int h = lane >> 5, lc = lane & 31;
    const int n = nb * 256 + wave * 32 + lc;

    // stage xh k-slice (32 tok x 1024 k) -> LDS, 16B chunks xor-swizzled
    #pragma unroll
    for (int i = 0; i < 8; ++i) {
        int f = i * 512 + tid, r = f >> 7, c = f & 127;
        i32x4 v = *(const i32x4*)(xh + (size_t)r * IN_F + ks * KCHUNK + c * 8);
        *(i32x4*)(xt + ((r * CH + (c ^ (r & 7))) << 3)) = v;
    }
    __syncthreads();

    const int* qrow = qidxs + (size_t)n * (IN_F / 8) + ks * (KCHUNK / 8);

#if HAVE_BUF
    __amdgpu_buffer_rsrc_t rsrc = __builtin_amdgcn_make_buffer_rsrc(
        (void*)cb, (short)0, 65536 * 16, 0x00020000);
    #define GA(ix, au) __builtin_bit_cast(bf16x8, \
        __builtin_amdgcn_raw_buffer_load_b128(rsrc, (ix) << 4, 0, au))
#else
    const bf16x8* cbv = (const bf16x8*)cb;
    #define GA(ix, au) (cbv[ix])
#endif

    f32x16 acc;
    #pragma unroll
    for (int i = 0; i < 16; ++i) acc[i] = 0.f;

    i32x4 iv[GROUPS];
    bf16x8 bfr[GROUPS][2];

    #pragma unroll
    for (int g = 0; g < DI; ++g)
        iv[g] = *(const i32x4*)(qrow + g * 4);
    #pragma unroll
    for (int g = 0; g < DG; ++g) {
        if (g & 1) {
            bfr[g][0] = GA(h ? iv[g][1] : iv[g][0], 1);
            bfr[g][1] = GA(h ? iv[g][3] : iv[g][2], 1);
        } else {
            bfr[g][0] = GA(h ? iv[g][1] : iv[g][0], 0);
            bfr[g][1] = GA(h ? iv[g][3] : iv[g][2], 0);
        }
    }

    #pragma unroll
    for (int g = 0; g < GROUPS; ++g) {
        if (g + DI < GROUPS)
            iv[g + DI] = *(const i32x4*)(qrow + (g + DI) * 4);
        if (g + DG < GROUPS) {
            if ((g + DG) & 1) {
                bfr[g + DG][0] = GA(h ? iv[g + DG][1] : iv[g + DG][0], 1);
                bfr[g + DG][1] = GA(h ? iv[g + DG][3] : iv[g + DG][2], 1);
            } else {
                bfr[g + DG][0] = GA(h ? iv[g + DG][1] : iv[g + DG][0], 0);
                bfr[g + DG][1] = GA(h ? iv[g + DG][3] : iv[g + DG][2], 0);
            }
        }
        #pragma unroll
        for (int sgi = 0; sgi < 2; ++sgi) {
            const int T = 2 * g + sgi;
            bf16x8 a = *(const bf16x8*)(xt +
                          ((lc * CH + ((2 * T + h) ^ (lc & 7))) << 3));
            acc = __builtin_amdgcn_mfma_f32_32x32x16_bf16(a, bfr[g][sgi],
                                                          acc, 0, 0, 0);
        }
    }
    #undef GA

    // D[m=(r&3)+4h+8(r>>2)][n=lc] -> bf16 partials
    __bf16* zp = zpart + ((size_t)ks * TOKENS) * OUT_F + n;
    #pragma unroll
    for (int r = 0; r < 16; ++r) {
        int m = (r & 3) + 4 * h + 8 * (r >> 2);
        zp[(size_t)m * OUT_F] = (__bf16)acc[r];
    }
}

// =================== cooperative mega-kernel (5 phases) ===================
__global__ __launch_bounds__(512, 2)
void fused_kernel(const float* __restrict__ x, const float* __restrict__ cb,
                  const int* __restrict__ qidxs, const float* __restrict__ su,
                  const float* __restrict__ sv,
                  const float* __restrict__ wscale, float* __restrict__ out,
                  __bf16* __restrict__ cbb, __bf16* __restrict__ xh,
                  __bf16* __restrict__ zpart, float* __restrict__ xw,
                  float* __restrict__ z1) {
    cg::grid_group grid = cg::this_grid();
    __shared__ __align__(16) char smem[65536];
    float* smf = (float*)smem;
    const int tid = threadIdx.x;
    const int bid = blockIdx.x;

    // phase 1: codebook cvt (all 131072 threads) + FWHT-8 of x*su -> xw
    cvt_body(cb, cbb, bid * 512 + tid);
    if (tid < 128)
        prepA_body(x, su, xw, bid * 128 + tid);      // 32768 tasks
    __threadfence();
    grid.sync();

    // phase 2: FWHT-1024 -> xh. 256 tasks, 2/block on blocks 0-127
    if (bid < 128)
        prepB_body(xw, xh, smf + (tid >> 8) * 1056,
                   bid * 2 + (tid >> 8), tid & 255);
    __threadfence();
    grid.sync();

    // phase 3: qgemm (gather wall, ~46us)
    qgemm_body(qidxs, cbb, xh, zpart, (__bf16*)smem, bid, tid);
    __threadfence();
    grid.sync();

    // phase 4: ks-sum + FWHT-1024 -> z1. 256 tasks, 2/block on blocks 0-127
    if (bid < 128)
        zsumA_body(zpart, z1, smf + (tid >> 8) * 1056,
                   bid * 2 + (tid >> 8), tid & 255);
    __threadfence();
    grid.sync();

    // phase 5: FWHT-8 + scale -> out
    if (tid < 128)
        zsumB_body(z1, sv, wscale, out, bid * 128 + tid);  // 32768 tasks
}

// =================== fallback: R13 five-kernel path ===================
__global__ __launch_bounds__(256)
void prepA_kernel(const float* __restrict__ x, const float* __restrict__ su,
                  float* __restrict__ xw) {
    prepA_body(x, su, xw, blockIdx.x * 256 + threadIdx.x);
}

__global__ __launch_bounds__(256)
void prepB_kernel(const float* __restrict__ cb, __bf16* __restrict__ cbb,
                  const float* __restrict__ xw, __bf16* __restrict__ xh) {
    __shared__ float st[1056];
    if (blockIdx.x < 512) {
        cvt_body(cb, cbb, blockIdx.x * 256 + threadIdx.x);
        return;
    }
    prepB_body(xw, xh, st, blockIdx.x - 512, threadIdx.x);
}

__global__ __launch_bounds__(512, 4)
void qgemm_kernel(const int* __restrict__ qidxs,
                  const __bf16* __restrict__ cb,
                  const __bf16* __restrict__ xh,
                  __bf16* __restrict__ zpart) {
    __shared__ __align__(16) __bf16 xt[TOKENS * KCHUNK];   // 64 KB
    qgemm_body(qidxs, cb, xh, zpart, xt, blockIdx.x, threadIdx.x);
}

__global__ __launch_bounds__(256)
void zsumA_kernel(const __bf16* __restrict__ zpart, float* __restrict__ z1) {
    __shared__ float st[1056];
    zsumA_body(zpart, z1, st, blockIdx.x, threadIdx.x);
}

__global__ __launch_bounds__(256)
void zsumB_kernel(const float* __restrict__ z1, const float* __restrict__ sv,
                  const float* __restrict__ wscale, float* __restrict__ out) {
    zsumB_body(z1, sv, wscale, out, blockIdx.x * 256 + threadIdx.x);
}

extern "C" void kernel_launch(void* const* d_in, const int* in_sizes, int n_in,
                              void* d_out, int out_size, void* d_ws, size_t ws_size,
                              hipStream_t stream) {
    const float* x      = (const float*)d_in[0];   // (32, 8192)
    const float* cb     = (const float*)d_in[1];   // (65536, 8)
    const int*   qidxs  = (const int*)d_in[2];     // (8192, 1024)
    const float* su     = (const float*)d_in[3];   // (8192,)
    const float* sv     = (const float*)d_in[4];   // (8192,)
    const float* wscale = (const float*)d_in[5];   // scalar
    float* out = (float*)d_out;                    // (32, 8192) fp32

    char* ws = (char*)d_ws;
    __bf16* cbb   = (__bf16*)ws;                               // 1 MB
    __bf16* xh    = (__bf16*)(ws + (1u << 20));                // 512 KB
    __bf16* zpart = (__bf16*)(ws + (1u << 20) + (512u << 10)); // 4 MB
    float*  xw    = (float*)(ws + (5u << 20) + (512u << 10));  // 1 MB
    float*  z1    = (float*)(ws + (6u << 20) + (512u << 10));  // 1 MB

    static int coop = -1;
    if (coop < 0) {
        int dev = 0;
        hipGetDevice(&dev);
        hipDeviceProp_t p{};
        hipGetDeviceProperties(&p, dev);
        coop = p.cooperativeLaunch ? 1 : 0;
    }

    if (coop) {
        void* kargs[] = { (void*)&x, (void*)&cb, (void*)&qidxs, (void*)&su,
                          (void*)&sv, (void*)&wscale, (void*)&out,
                          (void*)&cbb, (void*)&xh, (void*)&zpart,
                          (void*)&xw, (void*)&z1 };
        hipLaunchCooperativeKernel((const void*)fused_kernel, dim3(256),
                                   dim3(512), kargs, 0, stream);
    } else {
        hipLaunchKernelGGL(prepA_kernel, dim3(128), dim3(256), 0, stream,
                           x, su, xw);
        hipLaunchKernelGGL(prepB_kernel, dim3(768), dim3(256), 0, stream,
                           cb, cbb, xw, xh);
        hipLaunchKernelGGL(qgemm_kernel, dim3(32 * KSPLIT), dim3(512), 0,
                           stream, qidxs, cbb, xh, zpart);
        hipLaunchKernelGGL(zsumA_kernel, dim3(256), dim3(256), 0, stream,
                           zpart, z1);
        hipLaunchKernelGGL(zsumB_kernel, dim3(128), dim3(256), 0, stream,
                           z1, sv, wscale, out);
    }
}

// Round 6
// 127.757 us; speedup vs baseline: 3.3409x; 3.3409x over previous
//
#include <hip/hip_runtime.h>
#include <hip/hip_bf16.h>

// QuIP#-style quantized linear. R16: 4-dispatch chain, request-light bodies.
// Constants ledger (R11-R15): qgemm = 46.5us per-CU vmem-request wall
// (32768 random 16B gathers/CU x ~3.4cy/lane-req; 8 structural nulls ->
// irreducible). Inter-kernel gap ~10-15us. cg::grid().sync() = ~67us/sync
// on 8 XCDs (R15: 335us fused kernel) -> cooperative fusion dead.
// Optimal structure under the ledger: fewest dispatches whose bodies stay
// <=16 coalesced requests/thread (R14: prep-side fusion free, zsum-side
// fusion +23us). Chain:
//   1. prep  (768 blk): cvt codebook->bf16 | fused H8+H1024 input FWHT
//   2. qgemm (256 blk): R11 champion VERBATIM (gather wall)
//   3. zsumA (256 blk): ks-sum (zpart read once) + H1024
//   4. zsumB (128 blk): strided H8 + scale*sv
// FWHT-1024 micro-opt: bits 2-7 via 6 __shfl_xor stages (lane bits, no
// barriers), bits 8-9 via one LDS exchange (1 barrier) -- replaces 4 LDS
// stages with 8 barriers. Exit layout unchanged: v[j] = elem tid + j*256.

typedef __attribute__((ext_vector_type(16))) float f32x16;
typedef __attribute__((ext_vector_type(8))) __bf16 bf16x8;
typedef __attribute__((ext_vector_type(4))) __bf16 bf16x4;
typedef __attribute__((ext_vector_type(4))) int i32x4;

#define IN_F 8192
#define OUT_F 8192
#define TOKENS 32
#define KSPLIT 8
#define KCHUNK 1024
#define CH (KCHUNK / 8)            // 128 16B-chunks per token row in LDS
#define GROUPS (KCHUNK / 32)       // 32 pipeline groups (4 codes each)
#define DG 5                       // gather lookahead (groups)
#define DI 7                       // idx lookahead (groups)
#define INV_SQRT_8192 0.011048543456039806f
#define PAD(i) ((i) + ((i) >> 5))

#if __has_builtin(__builtin_amdgcn_raw_buffer_load_b128) && \
    __has_builtin(__builtin_amdgcn_make_buffer_rsrc)
#define HAVE_BUF 1
#else
#define HAVE_BUF 0
#endif

// ---- H4 butterfly over v[0..3] (2 bits) ----
__device__ inline void h4_reg(float v[4]) {
    float t0 = v[0] + v[1], t1 = v[0] - v[1];
    float t2 = v[2] + v[3], t3 = v[2] - v[3];
    v[0] = t0 + t2; v[1] = t1 + t3; v[2] = t0 - t2; v[3] = t1 - t3;
}

// ---- FWHT-1024, 256 threads. entry: v[j] = elem 4*tid+j.
// exit: v[j] = elem tid + j*256. 1 barrier total.
__device__ inline void fwht1024(float v[4], float* st, int tid) {
    h4_reg(v);                                   // bits 0-1 (j)
    const int lane = tid & 63;
    #pragma unroll
    for (int m = 1; m < 64; m <<= 1) {           // bits 2-7 (lane bits)
        #pragma unroll
        for (int j = 0; j < 4; ++j) {
            float p = __shfl_xor(v[j], m, 64);
            v[j] = (lane & m) ? (p - v[j]) : (v[j] + p);
        }
    }
    #pragma unroll
    for (int j = 0; j < 4; ++j) st[PAD(4 * tid + j)] = v[j];
    __syncthreads();                             // bits 8-9 via LDS exchange
    #pragma unroll
    for (int j = 0; j < 4; ++j) v[j] = st[PAD(tid + j * 256)];
    h4_reg(v);                                   // bits 8-9
}

// ---- kernel 1: codebook cvt (blocks<512) + fused H8+H1024 input FWHT ----
__global__ __launch_bounds__(256)
void prep_kernel(const float* __restrict__ cb, __bf16* __restrict__ cbb,
                 const float* __restrict__ x, const float* __restrict__ su,
                 __bf16* __restrict__ xh) {
    __shared__ float st[1056];
    const int tid = threadIdx.x;
    if (blockIdx.x < 512) {
        int i = blockIdx.x * 256 + tid;
        float4 vv = ((const float4*)cb)[i];
        bf16x4 o;
        o[0] = (__bf16)vv.x; o[1] = (__bf16)vv.y;
        o[2] = (__bf16)vv.z; o[3] = (__bf16)vv.w;
        ((bf16x4*)cbb)[i] = o;
        return;
    }
    const int id = blockIdx.x - 512;                 // 256 fwht tasks
    const int t = id >> 3, ch = id & 7;
    float sgn[8];
    #pragma unroll
    for (int k = 0; k < 8; ++k)
        sgn[k] = (__builtin_popcount(ch & k) & 1) ? -1.f : 1.f;
    // v[c] = sum_k sgn[k] * x[t, k*1024 + tid*4+c] * su[...]  (H8 row ch)
    float v[4] = {0.f, 0.f, 0.f, 0.f};
    #pragma unroll
    for (int k = 0; k < 8; ++k) {
        float4 xv = *(const float4*)(x + (size_t)t * IN_F + k * 1024 + tid * 4);
        float4 s4 = *(const float4*)(su + k * 1024 + tid * 4);
        v[0] += sgn[k] * xv.x * s4.x;
        v[1] += sgn[k] * xv.y * s4.y;
        v[2] += sgn[k] * xv.z * s4.z;
        v[3] += sgn[k] * xv.w * s4.w;
    }
    fwht1024(v, st, tid);
    __bf16* dst = xh + (size_t)t * IN_F + ch * 1024;
    #pragma unroll
    for (int j = 0; j < 4; ++j)
        dst[tid + j * 256] = (__bf16)(v[j] * INV_SQRT_8192);
}

// ---------------- kernel 2: zpart = xh @ W^T (R11 champion, verbatim) -----
__global__ __launch_bounds__(512, 4)
void qgemm_kernel(const int* __restrict__ qidxs,
                  const __bf16* __restrict__ cb,
                  const __bf16* __restrict__ xh,
                  __bf16* __restrict__ zpart) {
    __shared__ __align__(16) __bf16 xt[TOKENS * KCHUNK];   // 64 KB
    const int ks = blockIdx.x & (KSPLIT - 1);
    const int nb = blockIdx.x >> 3;
    const int tid = threadIdx.x;
    const int wave = tid >> 6, lane = tid & 63;
    const int h = lane >> 5, lc = lane & 31;
    const int n = nb * 256 + wave * 32 + lc;

    // stage xh k-slice (32 tok x 1024 k) -> LDS, 16B chunks xor-swizzled
    #pragma unroll
    for (int i = 0; i < 8; ++i) {
        int f = i * 512 + tid, r = f >> 7, c = f & 127;
        i32x4 v = *(const i32x4*)(xh + (size_t)r * IN_F + ks * KCHUNK + c * 8);
        *(i32x4*)(xt + ((r * CH + (c ^ (r & 7))) << 3)) = v;
    }
    __syncthreads();    // the only barrier

    const int* qrow = qidxs + (size_t)n * (IN_F / 8) + ks * (KCHUNK / 8);

#if HAVE_BUF
    // SRD over the bf16 codebook (1 MB). aux=1 -> SC0: L1-bypass, L2-cached.
    __amdgpu_buffer_rsrc_t rsrc = __builtin_amdgcn_make_buffer_rsrc(
        (void*)cb, (short)0, 65536 * 16, 0x00020000);
    #define GA(ix, au) __builtin_bit_cast(bf16x8, \
        __builtin_amdgcn_raw_buffer_load_b128(rsrc, (ix) << 4, 0, au))
#else
    const bf16x8* cbv = (const bf16x8*)cb;
    #define GA(ix, au) (cbv[ix])
#endif

    f32x16 acc;
    #pragma unroll
    for (int i = 0; i < 16; ++i) acc[i] = 0.f;

    i32x4 iv[GROUPS];
    bf16x8 bfr[GROUPS][2];

    #pragma unroll
    for (int g = 0; g < DI; ++g)
        iv[g] = *(const i32x4*)(qrow + g * 4);
    #pragma unroll
    for (int g = 0; g < DG; ++g) {
        if (g & 1) {
            bfr[g][0] = GA(h ? iv[g][1] : iv[g][0], 1);
            bfr[g][1] = GA(h ? iv[g][3] : iv[g][2], 1);
        } else {
            bfr[g][0] = GA(h ? iv[g][1] : iv[g][0], 0);
            bfr[g][1] = GA(h ? iv[g][3] : iv[g][2], 0);
        }
    }

    #pragma unroll
    for (int g = 0; g < GROUPS; ++g) {
        if (g + DI < GROUPS)
            iv[g + DI] = *(const i32x4*)(qrow + (g + DI) * 4);
        if (g + DG < GROUPS) {
            if ((g + DG) & 1) {
                bfr[g + DG][0] = GA(h ? iv[g + DG][1] : iv[g + DG][0], 1);
                bfr[g + DG][1] = GA(h ? iv[g + DG][3] : iv[g + DG][2], 1);
            } else {
                bfr[g + DG][0] = GA(h ? iv[g + DG][1] : iv[g + DG][0], 0);
                bfr[g + DG][1] = GA(h ? iv[g + DG][3] : iv[g + DG][2], 0);
            }
        }
        #pragma unroll
        for (int sgi = 0; sgi < 2; ++sgi) {
            const int T = 2 * g + sgi;
            bf16x8 a = *(const bf16x8*)(xt +
                          ((lc * CH + ((2 * T + h) ^ (lc & 7))) << 3));
            acc = __builtin_amdgcn_mfma_f32_32x32x16_bf16(a, bfr[g][sgi],
                                                          acc, 0, 0, 0);
        }
    }

    // D[m=(r&3)+4h+8(r>>2)][n=lc] -> bf16 partials
    __bf16* zp = zpart + ((size_t)ks * TOKENS) * OUT_F + n;
    #pragma unroll
    for (int r = 0; r < 16; ++r) {
        int m = (r & 3) + 4 * h + 8 * (r >> 2);
        zp[(size_t)m * OUT_F] = (__bf16)acc[r];
    }
}

// ---- kernel 3: z1 = FWHT1024(sum_ks zpart), zpart read exactly once -----
__global__ __launch_bounds__(256)
void zsumA_kernel(const __bf16* __restrict__ zpart, float* __restrict__ z1) {
    __shared__ float st[1056];
    const int tid = threadIdx.x;
    const int t = blockIdx.x >> 3, ch = blockIdx.x & 7;  // 256 blocks
    float v[4] = {0.f, 0.f, 0.f, 0.f};
    #pragma unroll
    for (int ks = 0; ks < KSPLIT; ++ks) {
        bf16x4 b = *(const bf16x4*)(zpart +
                     ((size_t)(ks * TOKENS + t)) * OUT_F + ch * 1024 + tid * 4);
        v[0] += (float)b[0]; v[1] += (float)b[1];
        v[2] += (float)b[2]; v[3] += (float)b[3];
    }
    fwht1024(v, st, tid);
    float* dst = z1 + (size_t)t * OUT_F + ch * 1024;
    #pragma unroll
    for (int j = 0; j < 4; ++j)
        dst[tid + j * 256] = v[j];
}

// ---- kernel 4: out = H8(bits 10-12 of z1) * scale * sv ------------------
__global__ __launch_bounds__(256)
void zsumB_kernel(const float* __restrict__ z1, const float* __restrict__ sv,
                  const float* __restrict__ wscale, float* __restrict__ out) {
    const int id = blockIdx.x * 256 + threadIdx.x;   // 32768 tasks
    const int t = id >> 10, c = id & 1023;
    float v[8];
    #pragma unroll
    for (int k = 0; k < 8; ++k)
        v[k] = z1[t * OUT_F + k * 1024 + c];
    #pragma unroll
    for (int h = 1; h < 8; h <<= 1)
        #pragma unroll
        for (int i = 0; i < 8; i += 2 * h)
            #pragma unroll
            for (int j = 0; j < h; ++j) {
                float a = v[i + j], b = v[i + j + h];
                v[i + j] = a + b;
                v[i + j + h] = a - b;
            }
    const float sc = INV_SQRT_8192 * wscale[0];
    #pragma unroll
    for (int k = 0; k < 8; ++k)
        out[t * OUT_F + k * 1024 + c] = v[k] * sc * sv[k * 1024 + c];
}

extern "C" void kernel_launch(void* const* d_in, const int* in_sizes, int n_in,
                              void* d_out, int out_size, void* d_ws, size_t ws_size,
                              hipStream_t stream) {
    const float* x      = (const float*)d_in[0];   // (32, 8192)
    const float* cb     = (const float*)d_in[1];   // (65536, 8)
    const int*   qidxs  = (const int*)d_in[2];     // (8192, 1024)
    const float* su     = (const float*)d_in[3];   // (8192,)
    const float* sv     = (const float*)d_in[4];   // (8192,)
    const float* wscale = (const float*)d_in[5];   // scalar
    float* out = (float*)d_out;                    // (32, 8192) fp32

    char* ws = (char*)d_ws;
    __bf16* cbb   = (__bf16*)ws;                               // 1 MB
    __bf16* xh    = (__bf16*)(ws + (1u << 20));                // 512 KB
    __bf16* zpart = (__bf16*)(ws + (1u << 20) + (512u << 10)); // 4 MB
    float*  z1    = (float*)(ws + (5u << 20) + (512u << 10));  // 1 MB

    hipLaunchKernelGGL(prep_kernel, dim3(768), dim3(256), 0, stream,
                       cb, cbb, x, su, xh);
    hipLaunchKernelGGL(qgemm_kernel, dim3(32 * KSPLIT), dim3(512), 0, stream,
                       qidxs, cbb, xh, zpart);
    hipLaunchKernelGGL(zsumA_kernel, dim3(256), dim3(256), 0, stream,
                       zpart, z1);
    hipLaunchKernelGGL(zsumB_kernel, dim3(128), dim3(256), 0, stream,
                       z1, sv, wscale, out);
}

// Round 7
// 127.701 us; speedup vs baseline: 3.3423x; 1.0004x over previous
//
#include <hip/hip_runtime.h>
#include <hip/hip_bf16.h>

// QuIP#-style quantized linear. R17: 3 dispatches, atomic ks-sum.
// Ledger (R11-R16, fits all rounds): dur = fill(46.5us, harness workspace
// re-poison, fixed) + qgemm(46.5us, per-CU vmem request wall: 32768 random
// 16B gathers/CU, 8 structural nulls -> irreducible) + small bodies(~12us)
// + ~7us per inter-kernel gap. R16 null vs R13 confirmed gap~7 (saved gap
// == added prep body). Levers left: gap count and zsum split.
// R17: qgemm epilogue atomicAdd's fp32 partials into z[32][8192] (1MB) --
// ks-sum becomes free (+~1K coalesced reqs/CU ~= +1.5us), zpart (4MB
// write + 4MB read) disappears, and zsum collapses to ONE light kernel:
// H8-first combine (8 coalesced float4 reads of L2-resident z) + H1024 +
// scale. z zeroed by prep's cvt-blocks (poison isn't zero). 2 gaps total.

typedef __attribute__((ext_vector_type(16))) float f32x16;
typedef __attribute__((ext_vector_type(8))) __bf16 bf16x8;
typedef __attribute__((ext_vector_type(4))) __bf16 bf16x4;
typedef __attribute__((ext_vector_type(4))) int i32x4;

#define IN_F 8192
#define OUT_F 8192
#define TOKENS 32
#define KSPLIT 8
#define KCHUNK 1024
#define CH (KCHUNK / 8)            // 128 16B-chunks per token row in LDS
#define GROUPS (KCHUNK / 32)       // 32 pipeline groups (4 codes each)
#define DG 5                       // gather lookahead (groups)
#define DI 7                       // idx lookahead (groups)
#define INV_SQRT_8192 0.011048543456039806f
#define PAD(i) ((i) + ((i) >> 5))

#if __has_builtin(__builtin_amdgcn_raw_buffer_load_b128) && \
    __has_builtin(__builtin_amdgcn_make_buffer_rsrc)
#define HAVE_BUF 1
#else
#define HAVE_BUF 0
#endif

// ---- H4 butterfly over v[0..3] (2 bits) ----
__device__ inline void h4_reg(float v[4]) {
    float t0 = v[0] + v[1], t1 = v[0] - v[1];
    float t2 = v[2] + v[3], t3 = v[2] - v[3];
    v[0] = t0 + t2; v[1] = t1 + t3; v[2] = t0 - t2; v[3] = t1 - t3;
}

// ---- FWHT-1024, 256 threads. entry: v[j] = elem 4*tid+j.
// exit: v[j] = elem tid + j*256. 1 barrier total.
__device__ inline void fwht1024(float v[4], float* st, int tid) {
    h4_reg(v);                                   // bits 0-1 (j)
    const int lane = tid & 63;
    #pragma unroll
    for (int m = 1; m < 64; m <<= 1) {           // bits 2-7 (lane bits)
        #pragma unroll
        for (int j = 0; j < 4; ++j) {
            float p = __shfl_xor(v[j], m, 64);
            v[j] = (lane & m) ? (p - v[j]) : (v[j] + p);
        }
    }
    #pragma unroll
    for (int j = 0; j < 4; ++j) st[PAD(4 * tid + j)] = v[j];
    __syncthreads();                             // bits 8-9 via LDS exchange
    #pragma unroll
    for (int j = 0; j < 4; ++j) v[j] = st[PAD(tid + j * 256)];
    h4_reg(v);                                   // bits 8-9
}

// ---- kernel 1: cvt + zero z (blocks<512) | fused H8+H1024 input FWHT ----
__global__ __launch_bounds__(256)
void prep_kernel(const float* __restrict__ cb, __bf16* __restrict__ cbb,
                 const float* __restrict__ x, const float* __restrict__ su,
                 __bf16* __restrict__ xh, float* __restrict__ z) {
    __shared__ float st[1056];
    const int tid = threadIdx.x;
    if (blockIdx.x < 512) {
        int i = blockIdx.x * 256 + tid;
        float4 vv = ((const float4*)cb)[i];
        bf16x4 o;
        o[0] = (__bf16)vv.x; o[1] = (__bf16)vv.y;
        o[2] = (__bf16)vv.z; o[3] = (__bf16)vv.w;
        ((bf16x4*)cbb)[i] = o;
        ((float2*)z)[i] = make_float2(0.f, 0.f);   // zero 1MB accumulator
        return;
    }
    const int id = blockIdx.x - 512;                 // 256 fwht tasks
    const int t = id >> 3, ch = id & 7;
    float sgn[8];
    #pragma unroll
    for (int k = 0; k < 8; ++k)
        sgn[k] = (__builtin_popcount(ch & k) & 1) ? -1.f : 1.f;
    // v[c] = sum_k sgn[k] * x[t, k*1024 + tid*4+c] * su[...]  (H8 row ch)
    float v[4] = {0.f, 0.f, 0.f, 0.f};
    #pragma unroll
    for (int k = 0; k < 8; ++k) {
        float4 xv = *(const float4*)(x + (size_t)t * IN_F + k * 1024 + tid * 4);
        float4 s4 = *(const float4*)(su + k * 1024 + tid * 4);
        v[0] += sgn[k] * xv.x * s4.x;
        v[1] += sgn[k] * xv.y * s4.y;
        v[2] += sgn[k] * xv.z * s4.z;
        v[3] += sgn[k] * xv.w * s4.w;
    }
    fwht1024(v, st, tid);
    __bf16* dst = xh + (size_t)t * IN_F + ch * 1024;
    #pragma unroll
    for (int j = 0; j < 4; ++j)
        dst[tid + j * 256] = (__bf16)(v[j] * INV_SQRT_8192);
}

// ---- kernel 2: z += xh @ W^T (R11 gather pipeline, atomic fp32 epilogue) -
__global__ __launch_bounds__(512, 4)
void qgemm_kernel(const int* __restrict__ qidxs,
                  const __bf16* __restrict__ cb,
                  const __bf16* __restrict__ xh,
                  float* __restrict__ z) {
    __shared__ __align__(16) __bf16 xt[TOKENS * KCHUNK];   // 64 KB
    const int ks = blockIdx.x & (KSPLIT - 1);
    const int nb = blockIdx.x >> 3;
    const int tid = threadIdx.x;
    const int wave = tid >> 6, lane = tid & 63;
    const int h = lane >> 5, lc = lane & 31;
    const int n = nb * 256 + wave * 32 + lc;

    // stage xh k-slice (32 tok x 1024 k) -> LDS, 16B chunks xor-swizzled
    #pragma unroll
    for (int i = 0; i < 8; ++i) {
        int f = i * 512 + tid, r = f >> 7, c = f & 127;
        i32x4 v = *(const i32x4*)(xh + (size_t)r * IN_F + ks * KCHUNK + c * 8);
        *(i32x4*)(xt + ((r * CH + (c ^ (r & 7))) << 3)) = v;
    }
    __syncthreads();    // the only barrier

    const int* qrow = qidxs + (size_t)n * (IN_F / 8) + ks * (KCHUNK / 8);

#if HAVE_BUF
    // SRD over the bf16 codebook (1 MB). aux=1 -> SC0: L1-bypass, L2-cached.
    __amdgpu_buffer_rsrc_t rsrc = __builtin_amdgcn_make_buffer_rsrc(
        (void*)cb, (short)0, 65536 * 16, 0x00020000);
    #define GA(ix, au) __builtin_bit_cast(bf16x8, \
        __builtin_amdgcn_raw_buffer_load_b128(rsrc, (ix) << 4, 0, au))
#else
    const bf16x8* cbv = (const bf16x8*)cb;
    #define GA(ix, au) (cbv[ix])
#endif

    f32x16 acc;
    #pragma unroll
    for (int i = 0; i < 16; ++i) acc[i] = 0.f;

    i32x4 iv[GROUPS];
    bf16x8 bfr[GROUPS][2];

    #pragma unroll
    for (int g = 0; g < DI; ++g)
        iv[g] = *(const i32x4*)(qrow + g * 4);
    #pragma unroll
    for (int g = 0; g < DG; ++g) {
        if (g & 1) {
            bfr[g][0] = GA(h ? iv[g][1] : iv[g][0], 1);
            bfr[g][1] = GA(h ? iv[g][3] : iv[g][2], 1);
        } else {
            bfr[g][0] = GA(h ? iv[g][1] : iv[g][0], 0);
            bfr[g][1] = GA(h ? iv[g][3] : iv[g][2], 0);
        }
    }

    #pragma unroll
    for (int g = 0; g < GROUPS; ++g) {
        if (g + DI < GROUPS)
            iv[g + DI] = *(const i32x4*)(qrow + (g + DI) * 4);
        if (g + DG < GROUPS) {
            if ((g + DG) & 1) {
                bfr[g + DG][0] = GA(h ? iv[g + DG][1] : iv[g + DG][0], 1);
                bfr[g + DG][1] = GA(h ? iv[g + DG][3] : iv[g + DG][2], 1);
            } else {
                bfr[g + DG][0] = GA(h ? iv[g + DG][1] : iv[g + DG][0], 0);
                bfr[g + DG][1] = GA(h ? iv[g + DG][3] : iv[g + DG][2], 0);
            }
        }
        #pragma unroll
        for (int sgi = 0; sgi < 2; ++sgi) {
            const int T = 2 * g + sgi;
            bf16x8 a = *(const bf16x8*)(xt +
                          ((lc * CH + ((2 * T + h) ^ (lc & 7))) << 3));
            acc = __builtin_amdgcn_mfma_f32_32x32x16_bf16(a, bfr[g][sgi],
                                                          acc, 0, 0, 0);
        }
    }

    // D[m=(r&3)+4h+8(r>>2)][n=lc] -> fp32 atomic ks-sum into z[t][n]
    #pragma unroll
    for (int r = 0; r < 16; ++r) {
        int m = (r & 3) + 4 * h + 8 * (r >> 2);
        atomicAdd(z + (size_t)m * OUT_F + n, acc[r]);
    }
}

// ---- kernel 3: out = H1024( H8-first(z) ) * scale * sv ------------------
__global__ __launch_bounds__(256)
void zsum_kernel(const float* __restrict__ z, const float* __restrict__ sv,
                 const float* __restrict__ wscale, float* __restrict__ out) {
    __shared__ float st[1056];
    const int tid = threadIdx.x;
    const int t = blockIdx.x >> 3, ch = blockIdx.x & 7;  // 256 blocks
    float sgn[8];
    #pragma unroll
    for (int k = 0; k < 8; ++k)
        sgn[k] = (__builtin_popcount(ch & k) & 1) ? -1.f : 1.f;
    // H8 row ch across chunks kk (z is L2-resident, 8 coalesced float4 reads)
    float v[4] = {0.f, 0.f, 0.f, 0.f};
    #pragma unroll
    for (int kk = 0; kk < 8; ++kk) {
        float4 zv = *(const float4*)(z + (size_t)t * OUT_F + kk * 1024 + tid * 4);
        v[0] += sgn[kk] * zv.x;
        v[1] += sgn[kk] * zv.y;
        v[2] += sgn[kk] * zv.z;
        v[3] += sgn[kk] * zv.w;
    }
    fwht1024(v, st, tid);
    const float sc = INV_SQRT_8192 * wscale[0];
    float* dst = out + (size_t)t * OUT_F + ch * 1024;
    const float* svp = sv + ch * 1024;
    #pragma unroll
    for (int j = 0; j < 4; ++j)
        dst[tid + j * 256] = v[j] * sc * svp[tid + j * 256];
}

extern "C" void kernel_launch(void* const* d_in, const int* in_sizes, int n_in,
                              void* d_out, int out_size, void* d_ws, size_t ws_size,
                              hipStream_t stream) {
    const float* x      = (const float*)d_in[0];   // (32, 8192)
    const float* cb     = (const float*)d_in[1];   // (65536, 8)
    const int*   qidxs  = (const int*)d_in[2];     // (8192, 1024)
    const float* su     = (const float*)d_in[3];   // (8192,)
    const float* sv     = (const float*)d_in[4];   // (8192,)
    const float* wscale = (const float*)d_in[5];   // scalar
    float* out = (float*)d_out;                    // (32, 8192) fp32

    char* ws = (char*)d_ws;
    __bf16* cbb = (__bf16*)ws;                                // 1 MB
    __bf16* xh  = (__bf16*)(ws + (1u << 20));                 // 512 KB
    float*  z   = (float*)(ws + (1u << 20) + (512u << 10));   // 1 MB fp32

    hipLaunchKernelGGL(prep_kernel, dim3(768), dim3(256), 0, stream,
                       cb, cbb, x, su, xh, z);
    hipLaunchKernelGGL(qgemm_kernel, dim3(32 * KSPLIT), dim3(512), 0, stream,
                       qidxs, cbb, xh, z);
    hipLaunchKernelGGL(zsum_kernel, dim3(256), dim3(256), 0, stream,
                       z, sv, wscale, out);
}